// Round 1
// baseline (107.568 us; speedup 1.0000x reference)
//
#include <hip/hip_runtime.h>

// Deformable unfold: x (4,64,128,128) f32, offset (4,18,128,128) f32
// out (4, 64*9, 128*128) f32;  out[b][c*9+k][s] = bilinear(x[b][c], py, px)
// py = oy + (ho-1+ky), px = ox + (wo-1+kx), oy=offset[b][2k][s], ox=offset[b][2k+1][s]

#define BB 4
#define CC 64
#define HH 128
#define WW 128
#define KK 9
#define HW (HH * WW)   // 16384 = 2^14

__global__ __launch_bounds__(256) void deform_unfold_kernel(
    const float* __restrict__ x, const float* __restrict__ off,
    float* __restrict__ out)
{
    int tid = blockIdx.x * 256 + threadIdx.x;
    // tid -> (b, k, s); s fastest for coalescing
    int s  = tid & (HW - 1);
    int bk = tid >> 14;
    if (bk >= BB * KK) return;
    int k = bk % KK;
    int b = bk / KK;

    int wo = s & (WW - 1);
    int ho = s >> 7;

    int ky = k / 3;
    int kx = k - ky * 3;

    // offset channels: (dg*K + k)*2 + {0:y, 1:x}; DG=1
    const float* offp = off + (((size_t)b * (2 * KK)) + 2 * k) * HW + s;
    float oy = offp[0];
    float ox = offp[HW];

    float py = oy + (float)(ho - 1 + ky);
    float px = ox + (float)(wo - 1 + kx);

    float y0f = floorf(py);
    float x0f = floorf(px);
    float wy1 = py - y0f;
    float wx1 = px - x0f;
    float wy0 = 1.0f - wy1;
    float wx0 = 1.0f - wx1;

    int y0 = (int)y0f;
    int x0 = (int)x0f;
    int y1 = y0 + 1;
    int x1 = x0 + 1;

    bool vy0 = (y0 >= 0) && (y0 < HH);
    bool vy1 = (y1 >= 0) && (y1 < HH);
    bool vx0 = (x0 >= 0) && (x0 < WW);
    bool vx1 = (x1 >= 0) && (x1 < WW);

    int y0c = min(max(y0, 0), HH - 1);
    int y1c = min(max(y1, 0), HH - 1);
    int x0c = min(max(x0, 0), WW - 1);
    int x1c = min(max(x1, 0), WW - 1);

    float w00 = wy0 * wx0 * ((vy0 && vx0) ? 1.0f : 0.0f);
    float w01 = wy0 * wx1 * ((vy0 && vx1) ? 1.0f : 0.0f);
    float w10 = wy1 * wx0 * ((vy1 && vx0) ? 1.0f : 0.0f);
    float w11 = wy1 * wx1 * ((vy1 && vx1) ? 1.0f : 0.0f);

    int o00 = y0c * WW + x0c;
    int o01 = y0c * WW + x1c;
    int o10 = y1c * WW + x0c;
    int o11 = y1c * WW + x1c;

    const float* xb = x + (size_t)b * CC * HW;
    // out flat index: ((b*CC + c)*KK + k)*HW + s
    float* ob = out + ((size_t)b * CC * KK + k) * HW + s;

    #pragma unroll 4
    for (int c = 0; c < CC; ++c) {
        const float* xc = xb + (size_t)c * HW;   // wave-uniform base step
        float v = xc[o00] * w00 + xc[o01] * w01 + xc[o10] * w10 + xc[o11] * w11;
        ob[(size_t)c * (KK * HW)] = v;
    }
}

extern "C" void kernel_launch(void* const* d_in, const int* in_sizes, int n_in,
                              void* d_out, int out_size, void* d_ws, size_t ws_size,
                              hipStream_t stream) {
    const float* x   = (const float*)d_in[0];
    const float* off = (const float*)d_in[1];
    float* out = (float*)d_out;

    int total = BB * KK * HW;                 // 589,824 threads
    int blocks = (total + 255) / 256;         // 2304 blocks
    deform_unfold_kernel<<<blocks, 256, 0, stream>>>(x, off, out);
}

// Round 2
// 39.884 us; speedup vs baseline: 2.6970x; 2.6970x over previous
//
#include <hip/hip_runtime.h>

// Deformable unfold: x (4,64,128,128) f32, offset (4,18,128,128) f32
// out (4, 64*9, 128*128) f32;  out[b][c*9+k][s] = bilinear(x[b][c], py, px)
//
// Strategy: block = (b, 2-row s-tile of 256, group of 8 channels).
// Stage 16 rows x 128 cols of 2 channels (interleaved float2, 16KB) in LDS;
// gather bilinear corners from LDS. Column-pair selection folded into
// precomputed pair weights (u0,u1 row0 / t0,t1 row1). Block-uniform fallback
// to direct global gather when any sample falls outside the 16-row window
// (P ~ 1e-7 per sample; exact correctness preserved).

#define BB 4
#define CC 64
#define HH 128
#define WW 128
#define KK 9
#define HW (HH * WW)    // 16384
#define NR 16           // staged rows per tile
#define CG 8            // channels per block
#define NG (CC / CG)    // 8 channel groups
#define TPB 256

__global__ __launch_bounds__(TPB) void deform_unfold_lds(
    const float* __restrict__ x, const float* __restrict__ off,
    float* __restrict__ out)
{
    __shared__ float2 tile[NR * WW];   // 16 KB, .x = ch c, .y = ch c+1
    __shared__ int anyfall;

    int tid = threadIdx.x;
    int bid = blockIdx.x;
    int g = bid & (NG - 1);
    int t = (bid >> 3) & 63;
    int b = bid >> 9;

    int s  = t * TPB + tid;
    int wo = s & (WW - 1);
    int ho = s >> 7;
    int r0 = 2 * t - 6;
    r0 = min(max(r0, 0), HH - NR);

    if (tid == 0) anyfall = 0;
    __syncthreads();

    // ---- per-(s,k) descriptors ----
    float u0[KK], u1[KK], t0w[KK], t1w[KK];
    int aA[KK], aB[KK];
    int myfall = 0;
    #pragma unroll
    for (int k = 0; k < KK; ++k) {
        int ky = k / 3, kx = k - ky * 3;
        float oy = off[(((size_t)b * (2 * KK)) + 2 * k) * HW + s];
        float ox = off[(((size_t)b * (2 * KK)) + 2 * k + 1) * HW + s];
        float py = oy + (float)(ho - 1 + ky);
        float px = ox + (float)(wo - 1 + kx);
        float y0f = floorf(py), x0f = floorf(px);
        float wy1 = py - y0f, wx1 = px - x0f;
        float wy0 = 1.f - wy1, wx0 = 1.f - wx1;
        int y0 = (int)y0f, x0 = (int)x0f;
        int y1 = y0 + 1, x1 = x0 + 1;
        bool vy0 = (y0 >= 0) && (y0 < HH), vy1 = (y1 >= 0) && (y1 < HH);
        bool vx0 = (x0 >= 0) && (x0 < WW), vx1 = (x1 >= 0) && (x1 < WW);
        int y0c = min(max(y0, 0), HH - 1), y1c = min(max(y1, 0), HH - 1);
        int xa  = min(max(x0, 0), WW - 2);          // pair base col: xa, xa+1
        int i0  = min(max(x0, 0), WW - 1) - xa;     // 0/1: which pair elem is x0c
        int i1  = min(max(x1, 0), WW - 1) - xa;     // 0/1: which pair elem is x1c
        float w00 = wy0 * wx0 * ((vy0 && vx0) ? 1.f : 0.f);
        float w01 = wy0 * wx1 * ((vy0 && vx1) ? 1.f : 0.f);
        float w10 = wy1 * wx0 * ((vy1 && vx0) ? 1.f : 0.f);
        float w11 = wy1 * wx1 * ((vy1 && vx1) ? 1.f : 0.f);
        // fold column selection into pair weights
        u0[k]  = (i0 == 0 ? w00 : 0.f) + (i1 == 0 ? w01 : 0.f);
        u1[k]  = (i0 == 1 ? w00 : 0.f) + (i1 == 1 ? w01 : 0.f);
        t0w[k] = (i0 == 0 ? w10 : 0.f) + (i1 == 0 ? w11 : 0.f);
        t1w[k] = (i0 == 1 ? w10 : 0.f) + (i1 == 1 ? w11 : 0.f);
        int rA = y0c - r0, rB = y1c - r0;
        myfall |= ((unsigned)rA >= NR) | ((unsigned)rB >= NR);
        rA = min(max(rA, 0), NR - 1);  // keep LDS addr safe; fall blocks branch away
        rB = min(max(rB, 0), NR - 1);
        aA[k] = rA * WW + xa;
        aB[k] = rB * WW + xa;
    }
    if (myfall) atomicOr(&anyfall, 1);
    __syncthreads();
    bool fall = (anyfall != 0);   // block-uniform

    int c0g = g * CG;
    const float* xb = x + ((size_t)b * CC + c0g) * HW;
    float* ob = out + (((size_t)b * CC + c0g) * KK) * HW + s;

    if (!fall) {
        for (int cp = 0; cp < CG / 2; ++cp) {
            // stage channels (c0g+2cp, c0g+2cp+1), rows r0..r0+NR-1
            const float4* s0 = (const float4*)(xb + ((size_t)(2 * cp)) * HW + (size_t)r0 * WW);
            const float4* s1 = (const float4*)(xb + ((size_t)(2 * cp) + 1) * HW + (size_t)r0 * WW);
            float4 a0 = s0[2 * tid], a1 = s0[2 * tid + 1];
            float4 b0 = s1[2 * tid], b1 = s1[2 * tid + 1];
            __syncthreads();                    // previous compute done
            float2* w = &tile[8 * tid];
            w[0] = make_float2(a0.x, b0.x); w[1] = make_float2(a0.y, b0.y);
            w[2] = make_float2(a0.z, b0.z); w[3] = make_float2(a0.w, b0.w);
            w[4] = make_float2(a1.x, b1.x); w[5] = make_float2(a1.y, b1.y);
            w[6] = make_float2(a1.z, b1.z); w[7] = make_float2(a1.w, b1.w);
            __syncthreads();
            float* o = ob + (size_t)(2 * cp) * KK * HW;
            #pragma unroll
            for (int k = 0; k < KK; ++k) {
                float2 p00 = tile[aA[k]], p01 = tile[aA[k] + 1];
                float2 p10 = tile[aB[k]], p11 = tile[aB[k] + 1];
                float vx_ = p00.x * u0[k] + p01.x * u1[k] + p10.x * t0w[k] + p11.x * t1w[k];
                float vy_ = p00.y * u0[k] + p01.y * u1[k] + p10.y * t0w[k] + p11.y * t1w[k];
                o[(size_t)k * HW] = vx_;
                o[(size_t)(KK * HW) + (size_t)k * HW] = vy_;
            }
        }
    } else {
        // exact slow path: direct global gather (round-1 math) for the whole block
        #pragma unroll 1
        for (int k = 0; k < KK; ++k) {
            int ky = k / 3, kx = k - ky * 3;
            float oy = off[(((size_t)b * (2 * KK)) + 2 * k) * HW + s];
            float ox = off[(((size_t)b * (2 * KK)) + 2 * k + 1) * HW + s];
            float py = oy + (float)(ho - 1 + ky);
            float px = ox + (float)(wo - 1 + kx);
            float y0f = floorf(py), x0f = floorf(px);
            float wy1 = py - y0f, wx1 = px - x0f;
            float wy0 = 1.f - wy1, wx0 = 1.f - wx1;
            int y0 = (int)y0f, x0 = (int)x0f;
            int y1 = y0 + 1, x1 = x0 + 1;
            bool vy0 = (y0 >= 0) && (y0 < HH), vy1 = (y1 >= 0) && (y1 < HH);
            bool vx0 = (x0 >= 0) && (x0 < WW), vx1 = (x1 >= 0) && (x1 < WW);
            int y0c = min(max(y0, 0), HH - 1), y1c = min(max(y1, 0), HH - 1);
            int x0c = min(max(x0, 0), WW - 1), x1c = min(max(x1, 0), WW - 1);
            float w00 = wy0 * wx0 * ((vy0 && vx0) ? 1.f : 0.f);
            float w01 = wy0 * wx1 * ((vy0 && vx1) ? 1.f : 0.f);
            float w10 = wy1 * wx0 * ((vy1 && vx0) ? 1.f : 0.f);
            float w11 = wy1 * wx1 * ((vy1 && vx1) ? 1.f : 0.f);
            int o00 = y0c * WW + x0c, o01 = y0c * WW + x1c;
            int o10 = y1c * WW + x0c, o11 = y1c * WW + x1c;
            #pragma unroll 1
            for (int c = 0; c < CG; ++c) {
                const float* xc = xb + (size_t)c * HW;
                (ob + (size_t)c * KK * HW)[(size_t)k * HW] =
                    xc[o00] * w00 + xc[o01] * w01 + xc[o10] * w10 + xc[o11] * w11;
            }
        }
    }
}

extern "C" void kernel_launch(void* const* d_in, const int* in_sizes, int n_in,
                              void* d_out, int out_size, void* d_ws, size_t ws_size,
                              hipStream_t stream) {
    const float* x   = (const float*)d_in[0];
    const float* off = (const float*)d_in[1];
    float* out = (float*)d_out;

    int blocks = BB * 64 * NG;   // 2048
    deform_unfold_lds<<<blocks, TPB, 0, stream>>>(x, off, out);
}

// Round 3
// 37.894 us; speedup vs baseline: 2.8387x; 1.0525x over previous
//
#include <hip/hip_runtime.h>

// Deformable unfold: x (4,64,128,128) f32, offset (4,18,128,128) f32
// out (4, 64*9, 128*128) f32;  out[b][c*9+k][s] = bilinear(x[b][c], py, px)
//
// Block = (b, 2-row s-tile of 256, group of 8 channels).
// Stage 16 rows x 128 cols of 2 channels (interleaved float2, 16KB) in LDS.
// v3 changes vs v2:
//  - conflict-free LDS staging writes: four ds_write_b128 per thread at 16B
//    lane stride (wt[tid+256*j]) instead of a 64B-contiguous per-lane run
//  - software pipeline: register-prefetch next channel pair during compute
//  - nontemporal output stores (147MB stream never re-read; keep L2 for x/off)

#define BB 4
#define CC 64
#define HH 128
#define WW 128
#define KK 9
#define HW (HH * WW)    // 16384
#define NR 16           // staged rows per tile
#define CG 8            // channels per block
#define NG (CC / CG)    // 8 channel groups
#define TPB 256

__global__ __launch_bounds__(TPB, 4) void deform_unfold_lds(
    const float* __restrict__ x, const float* __restrict__ off,
    float* __restrict__ out)
{
    __shared__ float2 tile[NR * WW];   // 16 KB, .x = ch c, .y = ch c+1
    __shared__ int anyfall;

    const int tid = threadIdx.x;
    const int bid = blockIdx.x;
    const int g = bid & (NG - 1);
    const int t = (bid >> 3) & 63;
    const int b = bid >> 9;

    const int s  = t * TPB + tid;
    const int wo = s & (WW - 1);
    const int ho = s >> 7;
    const int r0 = min(max(2 * t - 6, 0), HH - NR);

    const int c0g = g * CG;
    const float* xb = x + ((size_t)b * CC + c0g) * HW;
    float* ob = out + (((size_t)b * CC + c0g) * KK) * HW + s;

    // ---- prologue: issue staging loads for cp=0 (latency hides under descriptors)
    float2 pa[4], pb[4];
    {
        const float2* A2 = (const float2*)(xb + (size_t)r0 * WW);
        const float2* B2 = (const float2*)(xb + HW + (size_t)r0 * WW);
        #pragma unroll
        for (int j = 0; j < 4; ++j) { pa[j] = A2[tid + 256 * j]; pb[j] = B2[tid + 256 * j]; }
    }

    if (tid == 0) anyfall = 0;
    __syncthreads();

    // ---- per-(s,k) descriptors ----
    float u0[KK], u1[KK], t0w[KK], t1w[KK];
    int aAB[KK];            // packed LDS element indices: aA | (aB<<16)
    int myfall = 0;
    #pragma unroll
    for (int k = 0; k < KK; ++k) {
        int ky = k / 3, kx = k - ky * 3;
        float oy = off[(((size_t)b * (2 * KK)) + 2 * k) * HW + s];
        float ox = off[(((size_t)b * (2 * KK)) + 2 * k + 1) * HW + s];
        float py = oy + (float)(ho - 1 + ky);
        float px = ox + (float)(wo - 1 + kx);
        float y0f = floorf(py), x0f = floorf(px);
        float wy1 = py - y0f, wx1 = px - x0f;
        float wy0 = 1.f - wy1, wx0 = 1.f - wx1;
        int y0 = (int)y0f, x0 = (int)x0f;
        int y1 = y0 + 1, x1 = x0 + 1;
        bool vy0 = (y0 >= 0) && (y0 < HH), vy1 = (y1 >= 0) && (y1 < HH);
        bool vx0 = (x0 >= 0) && (x0 < WW), vx1 = (x1 >= 0) && (x1 < WW);
        int y0c = min(max(y0, 0), HH - 1), y1c = min(max(y1, 0), HH - 1);
        int xa  = min(max(x0, 0), WW - 2);          // pair base col: xa, xa+1
        int i0  = min(max(x0, 0), WW - 1) - xa;     // 0/1: which pair elem is x0c
        int i1  = min(max(x1, 0), WW - 1) - xa;     // 0/1: which pair elem is x1c
        float w00 = wy0 * wx0 * ((vy0 && vx0) ? 1.f : 0.f);
        float w01 = wy0 * wx1 * ((vy0 && vx1) ? 1.f : 0.f);
        float w10 = wy1 * wx0 * ((vy1 && vx0) ? 1.f : 0.f);
        float w11 = wy1 * wx1 * ((vy1 && vx1) ? 1.f : 0.f);
        u0[k]  = (i0 == 0 ? w00 : 0.f) + (i1 == 0 ? w01 : 0.f);
        u1[k]  = (i0 == 1 ? w00 : 0.f) + (i1 == 1 ? w01 : 0.f);
        t0w[k] = (i0 == 0 ? w10 : 0.f) + (i1 == 0 ? w11 : 0.f);
        t1w[k] = (i0 == 1 ? w10 : 0.f) + (i1 == 1 ? w11 : 0.f);
        int rA = y0c - r0, rB = y1c - r0;
        myfall |= ((unsigned)rA >= NR) | ((unsigned)rB >= NR);
        rA = min(max(rA, 0), NR - 1);
        rB = min(max(rB, 0), NR - 1);
        aAB[k] = (rA * WW + xa) | ((rB * WW + xa) << 16);
    }
    if (myfall) atomicOr(&anyfall, 1);
    __syncthreads();
    const bool fall = (anyfall != 0);   // block-uniform

    if (!fall) {
        #pragma unroll
        for (int cp = 0; cp < CG / 2; ++cp) {
            // conflict-free staging write: 16B lane stride
            float4* wt = (float4*)tile;
            #pragma unroll
            for (int j = 0; j < 4; ++j)
                wt[tid + 256 * j] = make_float4(pa[j].x, pb[j].x, pa[j].y, pb[j].y);
            // prefetch next channel pair into regs (hides under compute)
            if (cp + 1 < CG / 2) {
                const float2* A2 = (const float2*)(xb + (size_t)(2 * cp + 2) * HW + (size_t)r0 * WW);
                const float2* B2 = (const float2*)(xb + (size_t)(2 * cp + 3) * HW + (size_t)r0 * WW);
                #pragma unroll
                for (int j = 0; j < 4; ++j) { pa[j] = A2[tid + 256 * j]; pb[j] = B2[tid + 256 * j]; }
            }
            __syncthreads();
            float* o = ob + (size_t)(2 * cp) * KK * HW;
            #pragma unroll
            for (int k = 0; k < KK; ++k) {
                int aA = aAB[k] & 0xffff, aB = aAB[k] >> 16;
                float2 p00 = tile[aA], p01 = tile[aA + 1];
                float2 p10 = tile[aB], p11 = tile[aB + 1];
                float vx_ = p00.x * u0[k] + p01.x * u1[k] + p10.x * t0w[k] + p11.x * t1w[k];
                float vy_ = p00.y * u0[k] + p01.y * u1[k] + p10.y * t0w[k] + p11.y * t1w[k];
                __builtin_nontemporal_store(vx_, o + (size_t)k * HW);
                __builtin_nontemporal_store(vy_, o + (size_t)(KK + k) * HW);
            }
            __syncthreads();
        }
    } else {
        // exact slow path: direct global gather for the whole block (rare)
        #pragma unroll 1
        for (int k = 0; k < KK; ++k) {
            int ky = k / 3, kx = k - ky * 3;
            float oy = off[(((size_t)b * (2 * KK)) + 2 * k) * HW + s];
            float ox = off[(((size_t)b * (2 * KK)) + 2 * k + 1) * HW + s];
            float py = oy + (float)(ho - 1 + ky);
            float px = ox + (float)(wo - 1 + kx);
            float y0f = floorf(py), x0f = floorf(px);
            float wy1 = py - y0f, wx1 = px - x0f;
            float wy0 = 1.f - wy1, wx0 = 1.f - wx1;
            int y0 = (int)y0f, x0 = (int)x0f;
            int y1 = y0 + 1, x1 = x0 + 1;
            bool vy0 = (y0 >= 0) && (y0 < HH), vy1 = (y1 >= 0) && (y1 < HH);
            bool vx0 = (x0 >= 0) && (x0 < WW), vx1 = (x1 >= 0) && (x1 < WW);
            int y0c = min(max(y0, 0), HH - 1), y1c = min(max(y1, 0), HH - 1);
            int x0c = min(max(x0, 0), WW - 1), x1c = min(max(x1, 0), WW - 1);
            float w00 = wy0 * wx0 * ((vy0 && vx0) ? 1.f : 0.f);
            float w01 = wy0 * wx1 * ((vy0 && vx1) ? 1.f : 0.f);
            float w10 = wy1 * wx0 * ((vy1 && vx0) ? 1.f : 0.f);
            float w11 = wy1 * wx1 * ((vy1 && vx1) ? 1.f : 0.f);
            int o00 = y0c * WW + x0c, o01 = y0c * WW + x1c;
            int o10 = y1c * WW + x0c, o11 = y1c * WW + x1c;
            #pragma unroll 1
            for (int c = 0; c < CG; ++c) {
                const float* xc = xb + (size_t)c * HW;
                (ob + (size_t)c * KK * HW)[(size_t)k * HW] =
                    xc[o00] * w00 + xc[o01] * w01 + xc[o10] * w10 + xc[o11] * w11;
            }
        }
    }
}

extern "C" void kernel_launch(void* const* d_in, const int* in_sizes, int n_in,
                              void* d_out, int out_size, void* d_ws, size_t ws_size,
                              hipStream_t stream) {
    const float* x   = (const float*)d_in[0];
    const float* off = (const float*)d_in[1];
    float* out = (float*)d_out;

    int blocks = BB * 64 * NG;   // 2048
    deform_unfold_lds<<<blocks, TPB, 0, stream>>>(x, off, out);
}